// Round 8
// baseline (341.142 us; speedup 1.0000x reference)
//
#include <hip/hip_runtime.h>
#include <math.h>

// ---------------------------------------------------------------------------
// DCTFrequencyEncoder: DCT2 -> mask(112x112) -> conv3x3(1->64)+BN+ReLU ->
// conv3x3(64->128)+BN+ReLU -> spatial mean -> linear(128->256)
//
// Mask sparsity: conv2 output non-constant only on A=[0,114)^2; outside A it
// takes one of 8 analytic per-channel constants (validated rounds 2-7).
// Round 8: conv2 keeps f=4/n=4 (1:4 ds_read:MFMA) but B-pipeline is two
// half-steps of 2 frags with Bf[2][2] ping-pong (16 VGPR) -- round 7's
// Bf[2][4] (32 VGPR) blew the 128-reg cap at (512,4) and spilled 94MB to
// scratch (WRITE_SIZE evidence). A-frags loaded once per step, reused.
// ---------------------------------------------------------------------------

#define NPIX 224
#define KEEP 112
#define H1DIM 115     // h1 computed on [0,115)^2
#define ADIM 114      // region A

typedef short bf16x8 __attribute__((ext_vector_type(8)));
typedef float f32x4  __attribute__((ext_vector_type(4)));

__device__ __forceinline__ unsigned short f2bf(float f) {
    unsigned int u = __float_as_uint(f);
    unsigned int r = (u + 0x7FFFu + ((u >> 16) & 1u)) >> 16;   // RNE
    return (unsigned short)r;
}

// ---- fused prep ----
// [0,49): basis Bst[n][k]=2cos(pi k(2n+1)/448) (k,n<112)
// [49,54): P[oc][tap] = sum_ic w2*c1 (5 blocks, c1 recomputed per block)
// [54]: fused conv1 weights ws1/wb1
// [55,91): w2f fragment packing:
//   frag_id=(tap*2+kc)*8+g16, elem=lane; bf16x8 of
//   w2[oc=g16*16+(lane&15)][ic=kc*32+(lane>>4)*8..+8][tap]
__global__ __launch_bounds__(256) void prep_kernel(
    const float* __restrict__ w1, const float* __restrict__ b1,
    const float* __restrict__ g1, const float* __restrict__ be1,
    const float* __restrict__ m1, const float* __restrict__ v1,
    const float* __restrict__ w2,
    float* __restrict__ Bst, float* __restrict__ P,
    float* __restrict__ ws1, float* __restrict__ wb1,
    uint4* __restrict__ w2f) {
    int bx = blockIdx.x, tid = threadIdx.x;
    if (bx < 49) {
        int idx = bx * 256 + tid;
        if (idx < KEEP * KEEP) {
            int n = idx / KEEP, k = idx - n * KEEP;
            double ang = 3.14159265358979323846 * (double)k * (2.0 * n + 1.0) / (2.0 * NPIX);
            Bst[n * KEEP + k] = (float)(2.0 * cos(ang));
        }
    } else if (bx < 54) {
        __shared__ float c1s[64];
        if (tid < 64) {
            float sc = g1[tid] * rsqrtf(v1[tid] + 1e-5f);
            c1s[tid] = fmaxf((b1[tid] - m1[tid]) * sc + be1[tid], 0.f);
        }
        __syncthreads();
        int idx = (bx - 49) * 256 + tid;
        if (idx < 128 * 9) {
            int oc = idx / 9, tap = idx - oc * 9;
            float s = 0.f;
            for (int ic = 0; ic < 64; ++ic)
                s = fmaf(w2[((size_t)oc * 64 + ic) * 9 + tap], c1s[ic], s);
            P[idx] = s;
        }
    } else if (bx == 54) {
        if (tid < 64) {
            float sc = g1[tid] * rsqrtf(v1[tid] + 1e-5f);
            wb1[tid] = (b1[tid] - m1[tid]) * sc + be1[tid];
            for (int t = 0; t < 9; ++t) ws1[tid * 9 + t] = w1[tid * 9 + t] * sc;
        }
    } else {
        int j = (bx - 55) * 256 + tid;   // uint4 index, total 9*2*8*64 = 9216
        if (j < 9216) {
            int t = j >> 10;             // /1024
            int r = j & 1023;
            int kc = (r >> 9) & 1;
            int g16 = (r >> 6) & 7;
            int lane = r & 63;
            int oc = g16 * 16 + (lane & 15);
            int ic0 = kc * 32 + (lane >> 4) * 8;
            union { unsigned short us[8]; uint4 v; } u;
#pragma unroll
            for (int q = 0; q < 8; ++q)
                u.us[q] = f2bf(w2[((size_t)oc * 64 + ic0 + q) * 9 + t]);
            w2f[j] = u.v;
        }
    }
}

// ---- DCT along W, symmetry-halved, 4 rows/block ----
__global__ __launch_bounds__(128) void dct_w_kernel(const float* __restrict__ x,
                                                    const float* __restrict__ Bst,
                                                    float* __restrict__ tmp1) {
    int blk = blockIdx.x;            // b*56 + rq ; covers rows 4rq..4rq+3 of image b
    int tid = threadIdx.x;
    __shared__ float eo[2][4][112];
    const float* rows = x + (size_t)blk * 4 * NPIX;
    for (int i = tid; i < 448; i += 128) {
        int r = i / 112, n = i - r * 112;
        float a = rows[r * NPIX + n], bv = rows[r * NPIX + 223 - n];
        eo[0][r][n] = a + bv;
        eo[1][r][n] = a - bv;
    }
    __syncthreads();
    int kw = tid;
    if (kw >= KEEP) return;
    const float* eop = &eo[kw & 1][0][0];
    float a0 = 0.f, a1 = 0.f, a2 = 0.f, a3 = 0.f;
    for (int n = 0; n < 112; ++n) {
        float bs = Bst[n * KEEP + kw];
        a0 = fmaf(eop[n], bs, a0);
        a1 = fmaf(eop[112 + n], bs, a1);
        a2 = fmaf(eop[224 + n], bs, a2);
        a3 = fmaf(eop[336 + n], bs, a3);
    }
    size_t base = (size_t)blk * 4 * KEEP + kw;
    tmp1[base] = a0; tmp1[base + 112] = a1; tmp1[base + 224] = a2; tmp1[base + 336] = a3;
}

// ---- DCT along H, symmetry-halved, 4 kh/block, 4-way h-split (512 thr) ----
__global__ __launch_bounds__(512) void dct_h_kernel(const float* __restrict__ tmp1,
                                                    const float* __restrict__ Bst,
                                                    float* __restrict__ Xd) {
    int kq = blockIdx.x, b = blockIdx.y;
    int tid = threadIdx.x;
    int kw = tid & 127, sub = tid >> 7;   // sub 0..3
    __shared__ float ps[3][4][112];
    const int kh0 = kq * 4;
    float a0 = 0.f, a1 = 0.f, a2 = 0.f, a3 = 0.f;
    if (kw < KEEP) {
        const float* t = tmp1 + (size_t)b * NPIX * KEEP + kw;
        for (int h = sub * 28; h < sub * 28 + 28; ++h) {
            float lo = t[(size_t)h * KEEP];
            float hi = t[(size_t)(223 - h) * KEEP];
            float e = lo + hi, o = lo - hi;
            const float* bs = Bst + h * KEEP + kh0;   // wave-uniform -> s_load
            a0 = fmaf(e, bs[0], a0);
            a1 = fmaf(o, bs[1], a1);
            a2 = fmaf(e, bs[2], a2);
            a3 = fmaf(o, bs[3], a3);
        }
        if (sub) {
            ps[sub - 1][0][kw] = a0; ps[sub - 1][1][kw] = a1;
            ps[sub - 1][2][kw] = a2; ps[sub - 1][3][kw] = a3;
        }
    }
    __syncthreads();
    if (sub == 0 && kw < KEEP) {
        a0 += ps[0][0][kw] + ps[1][0][kw] + ps[2][0][kw];
        a1 += ps[0][1][kw] + ps[1][1][kw] + ps[2][1][kw];
        a2 += ps[0][2][kw] + ps[1][2][kw] + ps[2][2][kw];
        a3 += ps[0][3][kw] + ps[1][3][kw] + ps[2][3][kw];
        float* X = Xd + ((size_t)b * KEEP + kh0) * KEEP + kw;
        X[0] = a0; X[112] = a1; X[224] = a2; X[336] = a3;
    }
}

// ---- conv1 + BN + ReLU on [0,115)^2 -> channel-last bf16 h1c[b][r][c][64] ----
__global__ __launch_bounds__(256) void conv1_kernel(const float* __restrict__ Xd,
                                                    const float* __restrict__ ws1,
                                                    const float* __restrict__ wb1,
                                                    unsigned short* __restrict__ h1c) {
    const int r = blockIdx.y, b = blockIdx.z;
    const int c0 = blockIdx.x * 32;
    const int tid = threadIdx.x;
    __shared__ float xs[3][36];       // rows r-1..r+1, cols c0-1..c0+32
    __shared__ float wsm[8][73];      // [icg][(ic&7)*9+t], +pad for bank spread
    __shared__ float wbs[64];
    const float* X = Xd + (size_t)b * KEEP * KEEP;
    for (int i = tid; i < 102; i += 256) {
        int dr = i / 34, dc = i - dr * 34;
        int rr = r - 1 + dr, cc = c0 - 1 + dc;
        xs[dr][dc] = ((unsigned)rr < (unsigned)KEEP && (unsigned)cc < (unsigned)KEEP)
                         ? X[rr * KEEP + cc] : 0.f;
    }
    for (int i = tid; i < 576; i += 256) {
        int ic = i / 9, t = i - ic * 9;
        wsm[ic >> 3][(ic & 7) * 9 + t] = ws1[i];
    }
    if (tid < 64) wbs[tid] = wb1[tid];
    __syncthreads();

    const int px = tid >> 3, icg = tid & 7;
    const int c = c0 + px;
    float xv[9];
#pragma unroll
    for (int ky = 0; ky < 3; ++ky)
#pragma unroll
        for (int kx = 0; kx < 3; ++kx) xv[ky * 3 + kx] = xs[ky][px + kx];

    union { unsigned short us[8]; uint4 v; } u;
#pragma unroll
    for (int j = 0; j < 8; ++j) {
        float s = wbs[icg * 8 + j];
#pragma unroll
        for (int t = 0; t < 9; ++t) s = fmaf(xv[t], wsm[icg][j * 9 + t], s);
        u.us[j] = f2bf(fmaxf(s, 0.f));
    }
    if (c < H1DIM) {
        unsigned short* dst = h1c + (((size_t)b * H1DIM + r) * H1DIM + c) * 64 + icg * 8;
        *reinterpret_cast<uint4*>(dst) = u.v;
    }
}

// ---- conv2 via bf16 MFMA: 9-tap shifted implicit GEMM, fused BN+ReLU+A-mask+sum ----
// grid (8 tc, 8 tr, 32 b), block 512 = 8 waves = 4 mg x 2 og.
// Wave: 4 M-frags (rows 4mg..4mg+3) x 4 N-frags (oc og*64..og*64+63).
// K-step split into 2 half-steps of 2 B-frags: Bf[2][2] ping-pong (16 VGPR),
// A-frags (16 VGPR) loaded once per step and reused by both halves.
__global__ __launch_bounds__(512, 4) void conv2_mfma_kernel(
    const unsigned short* __restrict__ h1c, const uint4* __restrict__ w2f,
    const float* __restrict__ b2, const float* __restrict__ g2,
    const float* __restrict__ be2, const float* __restrict__ m2,
    const float* __restrict__ v2, float* __restrict__ partial) {
    const int tc = blockIdx.x, tr = blockIdx.y, b = blockIdx.z;
    const int r0 = tr * 16, c0 = tc * 16;
    const int tid = threadIdx.x;
    const int lane = tid & 63, w = tid >> 6;
    const int mg = w & 3, og = w >> 2;
    const int l15 = lane & 15, h4 = lane >> 4;

    __shared__ unsigned short At[324 * 64];   // 41472 B, XOR-swizzled

    // stage A tile: rows r0-1..r0+16, cols c0-1..c0+16, 64 ic = 8 granules of 16B
    const unsigned short* __restrict__ h1b = h1c + (size_t)b * (H1DIM * H1DIM * 64);
    for (int e = tid; e < 2592; e += 512) {
        int px = e >> 3, gi = e & 7;
        int pr = px / 18, pc = px - pr * 18;
        int gr = r0 + pr - 1, gc = c0 + pc - 1;
        uint4 v = make_uint4(0u, 0u, 0u, 0u);
        if ((unsigned)gr < (unsigned)H1DIM && (unsigned)gc < (unsigned)H1DIM)
            v = *reinterpret_cast<const uint4*>(h1b + ((size_t)(gr * H1DIM + gc)) * 64 + gi * 8);
        *reinterpret_cast<uint4*>(&At[px * 64 + ((gi * 8) ^ ((px & 7) << 3))]) = v;
    }
    __syncthreads();

    f32x4 acc[4][4];
#pragma unroll
    for (int f = 0; f < 4; ++f)
#pragma unroll
        for (int n = 0; n < 4; ++n) acc[f][n] = (f32x4){0.f, 0.f, 0.f, 0.f};

    // rows handled by this wave: r0+4mg .. r0+4mg+3 ; f valid iff f < flim
    const int flim = ADIM - (r0 + 4 * mg);   // wave-uniform
    if (flim > 0) {
        bf16x8 Bf[2][2];
        bf16x8 Af[4];
        // LOADB(buf, t, kc, h): 2 coalesced 1KB fragment loads
#define LOADB(buf, t, kc, h)                                                            \
    {                                                                                   \
        const uint4* bp = w2f + (size_t)(((t) * 2 + (kc)) * 8 + og * 4 + (h) * 2) * 64 + lane; \
        Bf[buf][0] = *reinterpret_cast<const bf16x8*>(bp);                              \
        Bf[buf][1] = *reinterpret_cast<const bf16x8*>(bp + 64);                         \
    }
        LOADB(0, 0, 0, 0);
#pragma unroll
        for (int sh = 0; sh < 36; ++sh) {
            const int s = sh >> 1, h = sh & 1;
            const int kc = s / 9, t = s - 9 * kc;
            if (sh + 1 < 36) {
                const int sn = (sh + 1) >> 1, hn = (sh + 1) & 1;
                const int nk = sn / 9, nt = sn - 9 * nk;
                LOADB((sh + 1) & 1, nt, nk, hn);
            }
            const int ky = t / 3, kx = t - 3 * ky;
            if (h == 0) {
#pragma unroll
                for (int f = 0; f < 4; ++f) {
                    const int px = (4 * mg + f + ky) * 18 + l15 + kx;
                    Af[f] = *reinterpret_cast<const bf16x8*>(
                        &At[px * 64 + ((kc * 32 + h4 * 8) ^ ((px & 7) << 3))]);
                }
            }
#pragma unroll
            for (int f = 0; f < 4; ++f) {
                if (f < flim) {                      // wave-uniform
                    acc[f][h * 2 + 0] = __builtin_amdgcn_mfma_f32_16x16x32_bf16(
                        Af[f], Bf[sh & 1][0], acc[f][h * 2 + 0], 0, 0, 0);
                    acc[f][h * 2 + 1] = __builtin_amdgcn_mfma_f32_16x16x32_bf16(
                        Af[f], Bf[sh & 1][1], acc[f][h * 2 + 1], 0, 0, 0);
                }
            }
        }
#undef LOADB
    }

    // epilogue: BN+ReLU, mask to region A, reduce over pixels, write partials
    const int tile = tr * 8 + tc;
    float* pslice = partial + (((size_t)b * 64 + tile) * 4 + mg) * 128;
#pragma unroll
    for (int n = 0; n < 4; ++n) {
        int oc = og * 64 + n * 16 + l15;
        float sc = g2[oc] * rsqrtf(v2[oc] + 1e-5f);
        float bias = b2[oc] - m2[oc];
        float add = be2[oc];
        float s = 0.f;
#pragma unroll
        for (int f = 0; f < 4; ++f) {
            int row = r0 + 4 * mg + f;
            bool rok = row < ADIM;
#pragma unroll
            for (int i = 0; i < 4; ++i) {
                int col = c0 + (h4 << 2) + i;
                float v = fmaxf(fmaf(acc[f][n][i] + bias, sc, add), 0.f);
                s += (rok && col < ADIM) ? v : 0.f;
            }
        }
        s += __shfl_xor(s, 16);
        s += __shfl_xor(s, 32);
        if (lane < 16) pslice[oc] = s;
    }
}

// ---- reduce partials + analytic constant regions -> mean[b][oc] ----
// grid (32 b, 8 ocg), 256 thr: thread (jq 0..15, ocl 0..15); 16-deep chains.
__global__ __launch_bounds__(256) void reduce_mean_kernel(
    const float* __restrict__ partial, const float* __restrict__ P,
    const float* __restrict__ b2, const float* __restrict__ g2,
    const float* __restrict__ be2, const float* __restrict__ m2,
    const float* __restrict__ v2, float* __restrict__ mean) {
    int b = blockIdx.x, ocg = blockIdx.y;
    int tid = threadIdx.x;
    int ocl = tid & 15, jq = tid >> 4;
    int oc = ocg * 16 + ocl;
    const float* pb = partial + (size_t)b * 256 * 128 + oc;
    float s = 0.f;
#pragma unroll
    for (int jj = 0; jj < 16; ++jj) s += pb[(size_t)(jq * 16 + jj) * 128];
    __shared__ float red[16][17];
    red[jq][ocl] = s;
    __syncthreads();
    if (jq == 0) {
        float tot = 0.f;
#pragma unroll
        for (int k = 0; k < 16; ++k) tot += red[k][ocl];

        float p[9];
#pragma unroll
        for (int t = 0; t < 9; ++t) p[t] = P[oc * 9 + t];

        float Sall = p[0] + p[1] + p[2] + p[3] + p[4] + p[5] + p[6] + p[7] + p[8];
        float Stop = p[3] + p[4] + p[5] + p[6] + p[7] + p[8];
        float Sbot = p[0] + p[1] + p[2] + p[3] + p[4] + p[5];
        float Sleft  = p[1] + p[2] + p[4] + p[5] + p[7] + p[8];
        float Sright = p[0] + p[1] + p[3] + p[4] + p[6] + p[7];
        float Ctr = p[3] + p[4] + p[6] + p[7];
        float Cbl = p[1] + p[2] + p[4] + p[5];
        float Cbr = p[0] + p[1] + p[3] + p[4];

        float bias = b2[oc], mm = m2[oc], bb = be2[oc];
        float sc = g2[oc] * rsqrtf(v2[oc] + 1e-5f);
#define VALOF(S) fmaxf(((bias) + (S) - (mm)) * (sc) + (bb), 0.f)
        float cs = 36515.f * VALOF(Sall) + 109.f * VALOF(Stop) + 109.f * VALOF(Sleft)
                 + 222.f * VALOF(Sbot) + 222.f * VALOF(Sright)
                 + VALOF(Ctr) + VALOF(Cbl) + VALOF(Cbr);
#undef VALOF
        mean[b * 128 + oc] = (tot + cs) * (1.f / (224.f * 224.f));
    }
}

// ---- final linear (float4 weight rows) ----
__global__ __launch_bounds__(256) void final_linear_kernel(const float* __restrict__ mean,
                                                           const float* __restrict__ wp,
                                                           const float* __restrict__ bp,
                                                           float* __restrict__ out) {
    int b = blockIdx.x, e = threadIdx.x;
    __shared__ float mrow[128];
    if (threadIdx.x < 128) mrow[threadIdx.x] = mean[b * 128 + threadIdx.x];
    __syncthreads();
    const float4* wr = reinterpret_cast<const float4*>(wp + (size_t)e * 128);
    float s = bp[e];
#pragma unroll 8
    for (int c = 0; c < 32; ++c) {
        float4 wv = wr[c];
        s = fmaf(mrow[4 * c], wv.x, s);
        s = fmaf(mrow[4 * c + 1], wv.y, s);
        s = fmaf(mrow[4 * c + 2], wv.z, s);
        s = fmaf(mrow[4 * c + 3], wv.w, s);
    }
    out[(size_t)b * 256 + e] = s;
}

extern "C" void kernel_launch(void* const* d_in, const int* in_sizes, int n_in,
                              void* d_out, int out_size, void* d_ws, size_t ws_size,
                              hipStream_t stream) {
    const float* x   = (const float*)d_in[0];
    const float* w1  = (const float*)d_in[1];
    const float* b1  = (const float*)d_in[2];
    const float* g1  = (const float*)d_in[3];
    const float* be1 = (const float*)d_in[4];
    const float* m1  = (const float*)d_in[5];
    const float* v1  = (const float*)d_in[6];
    const float* w2  = (const float*)d_in[7];
    const float* b2  = (const float*)d_in[8];
    const float* g2  = (const float*)d_in[9];
    const float* be2 = (const float*)d_in[10];
    const float* m2  = (const float*)d_in[11];
    const float* v2  = (const float*)d_in[12];
    const float* wp  = (const float*)d_in[13];
    const float* bp  = (const float*)d_in[14];
    float* out = (float*)d_out;

    float* ws = (float*)d_ws;
    size_t off = 0;
    float* Bst  = ws + off; off += (size_t)KEEP * KEEP;          // 12544
    float* tmp1 = ws + off; off += (size_t)32 * NPIX * KEEP;     // 802816
    float* Xd   = ws + off; off += (size_t)32 * KEEP * KEEP;     // 401408
    float* P    = ws + off; off += 128 * 9;
    float* ws1  = ws + off; off += 64 * 9;
    float* wb1  = ws + off; off += 64;
    uint4* w2f  = (uint4*)(ws + off); off += (size_t)9216 * 4;   // 9216 uint4
    float* part = ws + off; off += (size_t)32 * 256 * 128;       // 1048576
    float* mean = ws + off; off += 32 * 128;
    unsigned short* h1c = (unsigned short*)(ws + off);
    off += (size_t)32 * H1DIM * H1DIM * 64 / 2;                  // bf16

    if (ws_size < off * sizeof(float)) return;  // workspace too small: fail visibly

    prep_kernel<<<dim3(91), dim3(256), 0, stream>>>(w1, b1, g1, be1, m1, v1, w2,
                                                    Bst, P, ws1, wb1, w2f);
    dct_w_kernel<<<dim3(32 * 56), dim3(128), 0, stream>>>(x, Bst, tmp1);
    dct_h_kernel<<<dim3(28, 32), dim3(512), 0, stream>>>(tmp1, Bst, Xd);
    conv1_kernel<<<dim3(4, H1DIM, 32), dim3(256), 0, stream>>>(Xd, ws1, wb1, h1c);
    conv2_mfma_kernel<<<dim3(8, 8, 32), dim3(512), 0, stream>>>(
        h1c, w2f, b2, g2, be2, m2, v2, part);
    reduce_mean_kernel<<<dim3(32, 8), dim3(256), 0, stream>>>(part, P, b2, g2, be2, m2, v2, mean);
    final_linear_kernel<<<dim3(32), dim3(256), 0, stream>>>(mean, wp, bp, out);
}

// Round 9
// 135.917 us; speedup vs baseline: 2.5099x; 2.5099x over previous
//
#include <hip/hip_runtime.h>
#include <math.h>

// ---------------------------------------------------------------------------
// DCTFrequencyEncoder: DCT2 -> mask(112x112) -> conv3x3(1->64)+BN+ReLU ->
// conv3x3(64->128)+BN+ReLU -> spatial mean -> linear(128->256)
//
// Mask sparsity: conv2 output non-constant only on A=[0,114)^2; outside A it
// takes one of 8 analytic per-channel constants (validated rounds 2-8).
// Round 9: conv2 on 32x32x16 MFMA. Wave = 2 M-frags(32px) x 2 N-frags(32oc);
// per K-step: 2 ds_read_b128 + 2 coalesced 1KB B-loads + 4 MFMA. acc=64 AGPR,
// transients 16 VGPR short-lived, NO manual multibuffering (rounds 7/8 showed
// manual ping-pong arrays blow the 128-reg cap at (512,4) and spill).
// ---------------------------------------------------------------------------

#define NPIX 224
#define KEEP 112
#define H1DIM 115     // h1 computed on [0,115)^2
#define ADIM 114      // region A

typedef short bf16x8 __attribute__((ext_vector_type(8)));
typedef float f32x4  __attribute__((ext_vector_type(4)));
typedef float f32x16 __attribute__((ext_vector_type(16)));

__device__ __forceinline__ unsigned short f2bf(float f) {
    unsigned int u = __float_as_uint(f);
    unsigned int r = (u + 0x7FFFu + ((u >> 16) & 1u)) >> 16;   // RNE
    return (unsigned short)r;
}

// ---- fused prep ----
// [0,49): basis Bst[n][k]=2cos(pi k(2n+1)/448) (k,n<112)
// [49,54): P[oc][tap] = sum_ic w2*c1 (5 blocks)
// [54]: fused conv1 weights ws1/wb1
// [55,91): w2f fragment packing for 32x32x16:
//   frag q=(tap*4+kc)*4+g32, lane l: bf16x8 of
//   w2[oc=g32*32+(l&31)][ic=kc*16+(l>>5)*8 ..+8][tap]
__global__ __launch_bounds__(256) void prep_kernel(
    const float* __restrict__ w1, const float* __restrict__ b1,
    const float* __restrict__ g1, const float* __restrict__ be1,
    const float* __restrict__ m1, const float* __restrict__ v1,
    const float* __restrict__ w2,
    float* __restrict__ Bst, float* __restrict__ P,
    float* __restrict__ ws1, float* __restrict__ wb1,
    uint4* __restrict__ w2f) {
    int bx = blockIdx.x, tid = threadIdx.x;
    if (bx < 49) {
        int idx = bx * 256 + tid;
        if (idx < KEEP * KEEP) {
            int n = idx / KEEP, k = idx - n * KEEP;
            double ang = 3.14159265358979323846 * (double)k * (2.0 * n + 1.0) / (2.0 * NPIX);
            Bst[n * KEEP + k] = (float)(2.0 * cos(ang));
        }
    } else if (bx < 54) {
        __shared__ float c1s[64];
        if (tid < 64) {
            float sc = g1[tid] * rsqrtf(v1[tid] + 1e-5f);
            c1s[tid] = fmaxf((b1[tid] - m1[tid]) * sc + be1[tid], 0.f);
        }
        __syncthreads();
        int idx = (bx - 49) * 256 + tid;
        if (idx < 128 * 9) {
            int oc = idx / 9, tap = idx - oc * 9;
            float s = 0.f;
            for (int ic = 0; ic < 64; ++ic)
                s = fmaf(w2[((size_t)oc * 64 + ic) * 9 + tap], c1s[ic], s);
            P[idx] = s;
        }
    } else if (bx == 54) {
        if (tid < 64) {
            float sc = g1[tid] * rsqrtf(v1[tid] + 1e-5f);
            wb1[tid] = (b1[tid] - m1[tid]) * sc + be1[tid];
            for (int t = 0; t < 9; ++t) ws1[tid * 9 + t] = w1[tid * 9 + t] * sc;
        }
    } else {
        int j = (bx - 55) * 256 + tid;   // uint4 index, total 144*64 = 9216
        if (j < 9216) {
            int q = j >> 6, lane = j & 63;
            int tap = q / 16, rem = q & 15;
            int kc = rem >> 2, g32 = rem & 3;
            int oc = g32 * 32 + (lane & 31);
            int ic0 = kc * 16 + (lane >> 5) * 8;
            union { unsigned short us[8]; uint4 v; } u;
#pragma unroll
            for (int t_ = 0; t_ < 8; ++t_)
                u.us[t_] = f2bf(w2[((size_t)oc * 64 + ic0 + t_) * 9 + tap]);
            w2f[j] = u.v;
        }
    }
}

// ---- DCT along W, symmetry-halved, 4 rows/block ----
__global__ __launch_bounds__(128) void dct_w_kernel(const float* __restrict__ x,
                                                    const float* __restrict__ Bst,
                                                    float* __restrict__ tmp1) {
    int blk = blockIdx.x;            // b*56 + rq ; covers rows 4rq..4rq+3 of image b
    int tid = threadIdx.x;
    __shared__ float eo[2][4][112];
    const float* rows = x + (size_t)blk * 4 * NPIX;
    for (int i = tid; i < 448; i += 128) {
        int r = i / 112, n = i - r * 112;
        float a = rows[r * NPIX + n], bv = rows[r * NPIX + 223 - n];
        eo[0][r][n] = a + bv;
        eo[1][r][n] = a - bv;
    }
    __syncthreads();
    int kw = tid;
    if (kw >= KEEP) return;
    const float* eop = &eo[kw & 1][0][0];
    float a0 = 0.f, a1 = 0.f, a2 = 0.f, a3 = 0.f;
    for (int n = 0; n < 112; ++n) {
        float bs = Bst[n * KEEP + kw];
        a0 = fmaf(eop[n], bs, a0);
        a1 = fmaf(eop[112 + n], bs, a1);
        a2 = fmaf(eop[224 + n], bs, a2);
        a3 = fmaf(eop[336 + n], bs, a3);
    }
    size_t base = (size_t)blk * 4 * KEEP + kw;
    tmp1[base] = a0; tmp1[base + 112] = a1; tmp1[base + 224] = a2; tmp1[base + 336] = a3;
}

// ---- DCT along H, symmetry-halved, 4 kh/block, 4-way h-split (512 thr) ----
__global__ __launch_bounds__(512) void dct_h_kernel(const float* __restrict__ tmp1,
                                                    const float* __restrict__ Bst,
                                                    float* __restrict__ Xd) {
    int kq = blockIdx.x, b = blockIdx.y;
    int tid = threadIdx.x;
    int kw = tid & 127, sub = tid >> 7;   // sub 0..3
    __shared__ float ps[3][4][112];
    const int kh0 = kq * 4;
    float a0 = 0.f, a1 = 0.f, a2 = 0.f, a3 = 0.f;
    if (kw < KEEP) {
        const float* t = tmp1 + (size_t)b * NPIX * KEEP + kw;
        for (int h = sub * 28; h < sub * 28 + 28; ++h) {
            float lo = t[(size_t)h * KEEP];
            float hi = t[(size_t)(223 - h) * KEEP];
            float e = lo + hi, o = lo - hi;
            const float* bs = Bst + h * KEEP + kh0;   // wave-uniform -> s_load
            a0 = fmaf(e, bs[0], a0);
            a1 = fmaf(o, bs[1], a1);
            a2 = fmaf(e, bs[2], a2);
            a3 = fmaf(o, bs[3], a3);
        }
        if (sub) {
            ps[sub - 1][0][kw] = a0; ps[sub - 1][1][kw] = a1;
            ps[sub - 1][2][kw] = a2; ps[sub - 1][3][kw] = a3;
        }
    }
    __syncthreads();
    if (sub == 0 && kw < KEEP) {
        a0 += ps[0][0][kw] + ps[1][0][kw] + ps[2][0][kw];
        a1 += ps[0][1][kw] + ps[1][1][kw] + ps[2][1][kw];
        a2 += ps[0][2][kw] + ps[1][2][kw] + ps[2][2][kw];
        a3 += ps[0][3][kw] + ps[1][3][kw] + ps[2][3][kw];
        float* X = Xd + ((size_t)b * KEEP + kh0) * KEEP + kw;
        X[0] = a0; X[112] = a1; X[224] = a2; X[336] = a3;
    }
}

// ---- conv1 + BN + ReLU on [0,115)^2 -> channel-last bf16 h1c[b][r][c][64] ----
__global__ __launch_bounds__(256) void conv1_kernel(const float* __restrict__ Xd,
                                                    const float* __restrict__ ws1,
                                                    const float* __restrict__ wb1,
                                                    unsigned short* __restrict__ h1c) {
    const int r = blockIdx.y, b = blockIdx.z;
    const int c0 = blockIdx.x * 32;
    const int tid = threadIdx.x;
    __shared__ float xs[3][36];       // rows r-1..r+1, cols c0-1..c0+32
    __shared__ float wsm[8][73];      // [icg][(ic&7)*9+t], +pad for bank spread
    __shared__ float wbs[64];
    const float* X = Xd + (size_t)b * KEEP * KEEP;
    for (int i = tid; i < 102; i += 256) {
        int dr = i / 34, dc = i - dr * 34;
        int rr = r - 1 + dr, cc = c0 - 1 + dc;
        xs[dr][dc] = ((unsigned)rr < (unsigned)KEEP && (unsigned)cc < (unsigned)KEEP)
                         ? X[rr * KEEP + cc] : 0.f;
    }
    for (int i = tid; i < 576; i += 256) {
        int ic = i / 9, t = i - ic * 9;
        wsm[ic >> 3][(ic & 7) * 9 + t] = ws1[i];
    }
    if (tid < 64) wbs[tid] = wb1[tid];
    __syncthreads();

    const int px = tid >> 3, icg = tid & 7;
    const int c = c0 + px;
    float xv[9];
#pragma unroll
    for (int ky = 0; ky < 3; ++ky)
#pragma unroll
        for (int kx = 0; kx < 3; ++kx) xv[ky * 3 + kx] = xs[ky][px + kx];

    union { unsigned short us[8]; uint4 v; } u;
#pragma unroll
    for (int j = 0; j < 8; ++j) {
        float s = wbs[icg * 8 + j];
#pragma unroll
        for (int t = 0; t < 9; ++t) s = fmaf(xv[t], wsm[icg][j * 9 + t], s);
        u.us[j] = f2bf(fmaxf(s, 0.f));
    }
    if (c < H1DIM) {
        unsigned short* dst = h1c + (((size_t)b * H1DIM + r) * H1DIM + c) * 64 + icg * 8;
        *reinterpret_cast<uint4*>(dst) = u.v;
    }
}

// ---- conv2 via bf16 MFMA 32x32x16: 9-tap shifted implicit GEMM ----
// grid (8 tc, 8 tr, 32 b), block 512 = 8 waves = 4 mg x 2 og.
// Wave: M-frags {2mg,2mg+1} (32 px each = 2 tile rows), N-frags {2og,2og+1}.
// Per K-step (36 total = 9 tap x 4 kc): 2 ds_read_b128 + 2x 1KB B-load + 4 MFMA.
__global__ __launch_bounds__(512, 4) void conv2_mfma_kernel(
    const unsigned short* __restrict__ h1c, const uint4* __restrict__ w2f,
    const float* __restrict__ b2, const float* __restrict__ g2,
    const float* __restrict__ be2, const float* __restrict__ m2,
    const float* __restrict__ v2, float* __restrict__ partial) {
    const int tc = blockIdx.x, tr = blockIdx.y, b = blockIdx.z;
    const int r0 = tr * 16, c0 = tc * 16;
    const int tid = threadIdx.x;
    const int lane = tid & 63, w = tid >> 6;
    const int mg = w & 3, og = w >> 2;

    __shared__ unsigned short At[324 * 64];   // 41472 B, XOR-swizzled

    // stage A tile: rows r0-1..r0+16, cols c0-1..c0+16, 64 ic = 8 granules of 16B
    const unsigned short* __restrict__ h1b = h1c + (size_t)b * (H1DIM * H1DIM * 64);
    for (int e = tid; e < 2592; e += 512) {
        int px = e >> 3, gi = e & 7;
        int pr = px / 18, pc = px - pr * 18;
        int gr = r0 + pr - 1, gc = c0 + pc - 1;
        uint4 v = make_uint4(0u, 0u, 0u, 0u);
        if ((unsigned)gr < (unsigned)H1DIM && (unsigned)gc < (unsigned)H1DIM)
            v = *reinterpret_cast<const uint4*>(h1b + ((size_t)(gr * H1DIM + gc)) * 64 + gi * 8);
        *reinterpret_cast<uint4*>(&At[px * 64 + ((gi * 8) ^ ((px & 7) << 3))]) = v;
    }
    __syncthreads();

    f32x16 acc[2][2];
#pragma unroll
    for (int F = 0; F < 2; ++F)
#pragma unroll
        for (int N = 0; N < 2; ++N)
#pragma unroll
            for (int i = 0; i < 16; ++i) acc[F][N][i] = 0.f;

    // wave rows: r0+4mg .. r0+4mg+3; M-frag F valid iff 2F < flim2 (wave-uniform)
    const int flim2 = ADIM - r0 - 4 * mg;
    if (flim2 > 0) {
        const int rowbase = 4 * mg + ((lane & 31) >> 4);
        const int colbase = lane & 15;
        const int khalf = (lane >> 5) * 8;
#pragma unroll
        for (int s = 0; s < 36; ++s) {
            const int tap = s >> 2, kc = s & 3;
            const int ky = tap / 3, kx = tap - 3 * ky;
            const int icoff = kc * 16 + khalf;
            const bf16x8* bq = reinterpret_cast<const bf16x8*>(
                w2f + (size_t)(((tap * 4 + kc) * 4) + og * 2) * 64 + lane);
            const bf16x8 b0 = bq[0];
            const bf16x8 b1 = bq[64];
#pragma unroll
            for (int F = 0; F < 2; ++F) {
                if (2 * F < flim2) {                 // wave-uniform
                    const int px = (rowbase + 2 * F + ky) * 18 + colbase + kx;
                    const bf16x8 a = *reinterpret_cast<const bf16x8*>(
                        &At[px * 64 + (icoff ^ ((px & 7) << 3))]);
                    acc[F][0] = __builtin_amdgcn_mfma_f32_32x32x16_bf16(a, b0, acc[F][0], 0, 0, 0);
                    acc[F][1] = __builtin_amdgcn_mfma_f32_32x32x16_bf16(a, b1, acc[F][1], 0, 0, 0);
                }
            }
        }
    }

    // epilogue: BN+ReLU, mask to region A, reduce over pixels, write partials
    // C/D 32x32 map: col(oc-within-32)=lane&31, m=(reg&3)+8*(reg>>2)+4*(lane>>5)
    const int tile = tr * 8 + tc;
    float* pslice = partial + (((size_t)b * 64 + tile) * 4 + mg) * 128;
#pragma unroll
    for (int N = 0; N < 2; ++N) {
        int oc = og * 64 + N * 32 + (lane & 31);
        float sc = g2[oc] * rsqrtf(v2[oc] + 1e-5f);
        float bias = b2[oc] - m2[oc];
        float add = be2[oc];
        float s = 0.f;
#pragma unroll
        for (int F = 0; F < 2; ++F) {
#pragma unroll
            for (int rg = 0; rg < 16; ++rg) {
                int m = (rg & 3) + 8 * (rg >> 2) + 4 * (lane >> 5);
                int p = ((2 * mg + F) << 5) + m;
                int row = r0 + (p >> 4);
                int col = c0 + (p & 15);
                float v = fmaxf(fmaf(acc[F][N][rg] + bias, sc, add), 0.f);
                s += (row < ADIM && col < ADIM) ? v : 0.f;
            }
        }
        s += __shfl_xor(s, 32);
        if (lane < 32) pslice[og * 64 + N * 32 + lane] = s;
    }
}

// ---- reduce partials + analytic constant regions -> mean[b][oc] ----
// grid (32 b, 8 ocg), 256 thr: thread (jq 0..15, ocl 0..15); 16-deep chains.
__global__ __launch_bounds__(256) void reduce_mean_kernel(
    const float* __restrict__ partial, const float* __restrict__ P,
    const float* __restrict__ b2, const float* __restrict__ g2,
    const float* __restrict__ be2, const float* __restrict__ m2,
    const float* __restrict__ v2, float* __restrict__ mean) {
    int b = blockIdx.x, ocg = blockIdx.y;
    int tid = threadIdx.x;
    int ocl = tid & 15, jq = tid >> 4;
    int oc = ocg * 16 + ocl;
    const float* pb = partial + (size_t)b * 256 * 128 + oc;
    float s = 0.f;
#pragma unroll
    for (int jj = 0; jj < 16; ++jj) s += pb[(size_t)(jq * 16 + jj) * 128];
    __shared__ float red[16][17];
    red[jq][ocl] = s;
    __syncthreads();
    if (jq == 0) {
        float tot = 0.f;
#pragma unroll
        for (int k = 0; k < 16; ++k) tot += red[k][ocl];

        float p[9];
#pragma unroll
        for (int t = 0; t < 9; ++t) p[t] = P[oc * 9 + t];

        float Sall = p[0] + p[1] + p[2] + p[3] + p[4] + p[5] + p[6] + p[7] + p[8];
        float Stop = p[3] + p[4] + p[5] + p[6] + p[7] + p[8];
        float Sbot = p[0] + p[1] + p[2] + p[3] + p[4] + p[5];
        float Sleft  = p[1] + p[2] + p[4] + p[5] + p[7] + p[8];
        float Sright = p[0] + p[1] + p[3] + p[4] + p[6] + p[7];
        float Ctr = p[3] + p[4] + p[6] + p[7];
        float Cbl = p[1] + p[2] + p[4] + p[5];
        float Cbr = p[0] + p[1] + p[3] + p[4];

        float bias = b2[oc], mm = m2[oc], bb = be2[oc];
        float sc = g2[oc] * rsqrtf(v2[oc] + 1e-5f);
#define VALOF(S) fmaxf(((bias) + (S) - (mm)) * (sc) + (bb), 0.f)
        float cs = 36515.f * VALOF(Sall) + 109.f * VALOF(Stop) + 109.f * VALOF(Sleft)
                 + 222.f * VALOF(Sbot) + 222.f * VALOF(Sright)
                 + VALOF(Ctr) + VALOF(Cbl) + VALOF(Cbr);
#undef VALOF
        mean[b * 128 + oc] = (tot + cs) * (1.f / (224.f * 224.f));
    }
}

// ---- final linear (float4 weight rows) ----
__global__ __launch_bounds__(256) void final_linear_kernel(const float* __restrict__ mean,
                                                           const float* __restrict__ wp,
                                                           const float* __restrict__ bp,
                                                           float* __restrict__ out) {
    int b = blockIdx.x, e = threadIdx.x;
    __shared__ float mrow[128];
    if (threadIdx.x < 128) mrow[threadIdx.x] = mean[b * 128 + threadIdx.x];
    __syncthreads();
    const float4* wr = reinterpret_cast<const float4*>(wp + (size_t)e * 128);
    float s = bp[e];
#pragma unroll 8
    for (int c = 0; c < 32; ++c) {
        float4 wv = wr[c];
        s = fmaf(mrow[4 * c], wv.x, s);
        s = fmaf(mrow[4 * c + 1], wv.y, s);
        s = fmaf(mrow[4 * c + 2], wv.z, s);
        s = fmaf(mrow[4 * c + 3], wv.w, s);
    }
    out[(size_t)b * 256 + e] = s;
}

extern "C" void kernel_launch(void* const* d_in, const int* in_sizes, int n_in,
                              void* d_out, int out_size, void* d_ws, size_t ws_size,
                              hipStream_t stream) {
    const float* x   = (const float*)d_in[0];
    const float* w1  = (const float*)d_in[1];
    const float* b1  = (const float*)d_in[2];
    const float* g1  = (const float*)d_in[3];
    const float* be1 = (const float*)d_in[4];
    const float* m1  = (const float*)d_in[5];
    const float* v1  = (const float*)d_in[6];
    const float* w2  = (const float*)d_in[7];
    const float* b2  = (const float*)d_in[8];
    const float* g2  = (const float*)d_in[9];
    const float* be2 = (const float*)d_in[10];
    const float* m2  = (const float*)d_in[11];
    const float* v2  = (const float*)d_in[12];
    const float* wp  = (const float*)d_in[13];
    const float* bp  = (const float*)d_in[14];
    float* out = (float*)d_out;

    float* ws = (float*)d_ws;
    size_t off = 0;
    float* Bst  = ws + off; off += (size_t)KEEP * KEEP;          // 12544
    float* tmp1 = ws + off; off += (size_t)32 * NPIX * KEEP;     // 802816
    float* Xd   = ws + off; off += (size_t)32 * KEEP * KEEP;     // 401408
    float* P    = ws + off; off += 128 * 9;
    float* ws1  = ws + off; off += 64 * 9;
    float* wb1  = ws + off; off += 64;
    uint4* w2f  = (uint4*)(ws + off); off += (size_t)9216 * 4;   // 9216 uint4
    float* part = ws + off; off += (size_t)32 * 256 * 128;       // 1048576
    float* mean = ws + off; off += 32 * 128;
    unsigned short* h1c = (unsigned short*)(ws + off);
    off += (size_t)32 * H1DIM * H1DIM * 64 / 2;                  // bf16

    if (ws_size < off * sizeof(float)) return;  // workspace too small: fail visibly

    prep_kernel<<<dim3(91), dim3(256), 0, stream>>>(w1, b1, g1, be1, m1, v1, w2,
                                                    Bst, P, ws1, wb1, w2f);
    dct_w_kernel<<<dim3(32 * 56), dim3(128), 0, stream>>>(x, Bst, tmp1);
    dct_h_kernel<<<dim3(28, 32), dim3(512), 0, stream>>>(tmp1, Bst, Xd);
    conv1_kernel<<<dim3(4, H1DIM, 32), dim3(256), 0, stream>>>(Xd, ws1, wb1, h1c);
    conv2_mfma_kernel<<<dim3(8, 8, 32), dim3(512), 0, stream>>>(
        h1c, w2f, b2, g2, be2, m2, v2, part);
    reduce_mean_kernel<<<dim3(32, 8), dim3(256), 0, stream>>>(part, P, b2, g2, be2, m2, v2, mean);
    final_linear_kernel<<<dim3(32), dim3(256), 0, stream>>>(mean, wp, bp, out);
}

// Round 10
// 125.085 us; speedup vs baseline: 2.7273x; 1.0866x over previous
//
#include <hip/hip_runtime.h>
#include <math.h>

// ---------------------------------------------------------------------------
// DCTFrequencyEncoder: DCT2 -> mask(112x112) -> conv3x3(1->64)+BN+ReLU ->
// conv3x3(64->128)+BN+ReLU -> spatial mean -> linear(128->256)
//
// Mask sparsity: conv2 output non-constant only on A=[0,114)^2; outside A it
// takes one of 8 analytic per-channel constants (validated rounds 2-9).
// Round 10: conv2 keeps 32x32x16 shape (round 9, no spill) but replaces the
// per-read address chain (~6 VALU) with precomputed XOR-addressable LDS
// layout: px*128 + 32*(kc^(px&3)) + 16*(h^((px>>2)&1)); per step 3 VALU.
// flim2>=4 path specialized branch-free. conv1 rewritten: thread=pixel,
// s_load (wave-uniform) weights, swizzled-LDS transpose for coalesced stores.
// ---------------------------------------------------------------------------

#define NPIX 224
#define KEEP 112
#define H1DIM 115     // h1 computed on [0,115)^2
#define NPX1 (H1DIM * H1DIM)
#define ADIM 114      // region A

typedef short bf16x8 __attribute__((ext_vector_type(8)));
typedef float f32x4  __attribute__((ext_vector_type(4)));
typedef float f32x16 __attribute__((ext_vector_type(16)));

__device__ __forceinline__ unsigned short f2bf(float f) {
    unsigned int u = __float_as_uint(f);
    unsigned int r = (u + 0x7FFFu + ((u >> 16) & 1u)) >> 16;   // RNE
    return (unsigned short)r;
}

// ---- fused prep ----
// [0,49): basis Bst[n][k]=2cos(pi k(2n+1)/448) (k,n<112)
// [49,54): P[oc][tap] = sum_ic w2*c1 (5 blocks)
// [54]: fused conv1 weights ws1/wb1
// [55,91): w2f fragment packing for 32x32x16:
//   frag q=(tap*4+kc)*4+g32, lane l: bf16x8 of
//   w2[oc=g32*32+(l&31)][ic=kc*16+(l>>5)*8 ..+8][tap]
__global__ __launch_bounds__(256) void prep_kernel(
    const float* __restrict__ w1, const float* __restrict__ b1,
    const float* __restrict__ g1, const float* __restrict__ be1,
    const float* __restrict__ m1, const float* __restrict__ v1,
    const float* __restrict__ w2,
    float* __restrict__ Bst, float* __restrict__ P,
    float* __restrict__ ws1, float* __restrict__ wb1,
    uint4* __restrict__ w2f) {
    int bx = blockIdx.x, tid = threadIdx.x;
    if (bx < 49) {
        int idx = bx * 256 + tid;
        if (idx < KEEP * KEEP) {
            int n = idx / KEEP, k = idx - n * KEEP;
            double ang = 3.14159265358979323846 * (double)k * (2.0 * n + 1.0) / (2.0 * NPIX);
            Bst[n * KEEP + k] = (float)(2.0 * cos(ang));
        }
    } else if (bx < 54) {
        __shared__ float c1s[64];
        if (tid < 64) {
            float sc = g1[tid] * rsqrtf(v1[tid] + 1e-5f);
            c1s[tid] = fmaxf((b1[tid] - m1[tid]) * sc + be1[tid], 0.f);
        }
        __syncthreads();
        int idx = (bx - 49) * 256 + tid;
        if (idx < 128 * 9) {
            int oc = idx / 9, tap = idx - oc * 9;
            float s = 0.f;
            for (int ic = 0; ic < 64; ++ic)
                s = fmaf(w2[((size_t)oc * 64 + ic) * 9 + tap], c1s[ic], s);
            P[idx] = s;
        }
    } else if (bx == 54) {
        if (tid < 64) {
            float sc = g1[tid] * rsqrtf(v1[tid] + 1e-5f);
            wb1[tid] = (b1[tid] - m1[tid]) * sc + be1[tid];
            for (int t = 0; t < 9; ++t) ws1[tid * 9 + t] = w1[tid * 9 + t] * sc;
        }
    } else {
        int j = (bx - 55) * 256 + tid;   // uint4 index, total 144*64 = 9216
        if (j < 9216) {
            int q = j >> 6, lane = j & 63;
            int tap = q / 16, rem = q & 15;
            int kc = rem >> 2, g32 = rem & 3;
            int oc = g32 * 32 + (lane & 31);
            int ic0 = kc * 16 + (lane >> 5) * 8;
            union { unsigned short us[8]; uint4 v; } u;
#pragma unroll
            for (int t_ = 0; t_ < 8; ++t_)
                u.us[t_] = f2bf(w2[((size_t)oc * 64 + ic0 + t_) * 9 + tap]);
            w2f[j] = u.v;
        }
    }
}

// ---- DCT along W, symmetry-halved, 4 rows/block ----
__global__ __launch_bounds__(128) void dct_w_kernel(const float* __restrict__ x,
                                                    const float* __restrict__ Bst,
                                                    float* __restrict__ tmp1) {
    int blk = blockIdx.x;            // b*56 + rq ; covers rows 4rq..4rq+3 of image b
    int tid = threadIdx.x;
    __shared__ float eo[2][4][112];
    const float* rows = x + (size_t)blk * 4 * NPIX;
    for (int i = tid; i < 448; i += 128) {
        int r = i / 112, n = i - r * 112;
        float a = rows[r * NPIX + n], bv = rows[r * NPIX + 223 - n];
        eo[0][r][n] = a + bv;
        eo[1][r][n] = a - bv;
    }
    __syncthreads();
    int kw = tid;
    if (kw >= KEEP) return;
    const float* eop = &eo[kw & 1][0][0];
    float a0 = 0.f, a1 = 0.f, a2 = 0.f, a3 = 0.f;
    for (int n = 0; n < 112; ++n) {
        float bs = Bst[n * KEEP + kw];
        a0 = fmaf(eop[n], bs, a0);
        a1 = fmaf(eop[112 + n], bs, a1);
        a2 = fmaf(eop[224 + n], bs, a2);
        a3 = fmaf(eop[336 + n], bs, a3);
    }
    size_t base = (size_t)blk * 4 * KEEP + kw;
    tmp1[base] = a0; tmp1[base + 112] = a1; tmp1[base + 224] = a2; tmp1[base + 336] = a3;
}

// ---- DCT along H, symmetry-halved, 4 kh/block, 4-way h-split (512 thr) ----
__global__ __launch_bounds__(512) void dct_h_kernel(const float* __restrict__ tmp1,
                                                    const float* __restrict__ Bst,
                                                    float* __restrict__ Xd) {
    int kq = blockIdx.x, b = blockIdx.y;
    int tid = threadIdx.x;
    int kw = tid & 127, sub = tid >> 7;   // sub 0..3
    __shared__ float ps[3][4][112];
    const int kh0 = kq * 4;
    float a0 = 0.f, a1 = 0.f, a2 = 0.f, a3 = 0.f;
    if (kw < KEEP) {
        const float* t = tmp1 + (size_t)b * NPIX * KEEP + kw;
        for (int h = sub * 28; h < sub * 28 + 28; ++h) {
            float lo = t[(size_t)h * KEEP];
            float hi = t[(size_t)(223 - h) * KEEP];
            float e = lo + hi, o = lo - hi;
            const float* bs = Bst + h * KEEP + kh0;   // wave-uniform -> s_load
            a0 = fmaf(e, bs[0], a0);
            a1 = fmaf(o, bs[1], a1);
            a2 = fmaf(e, bs[2], a2);
            a3 = fmaf(o, bs[3], a3);
        }
        if (sub) {
            ps[sub - 1][0][kw] = a0; ps[sub - 1][1][kw] = a1;
            ps[sub - 1][2][kw] = a2; ps[sub - 1][3][kw] = a3;
        }
    }
    __syncthreads();
    if (sub == 0 && kw < KEEP) {
        a0 += ps[0][0][kw] + ps[1][0][kw] + ps[2][0][kw];
        a1 += ps[0][1][kw] + ps[1][1][kw] + ps[2][1][kw];
        a2 += ps[0][2][kw] + ps[1][2][kw] + ps[2][2][kw];
        a3 += ps[0][3][kw] + ps[1][3][kw] + ps[2][3][kw];
        float* X = Xd + ((size_t)b * KEEP + kh0) * KEEP + kw;
        X[0] = a0; X[112] = a1; X[224] = a2; X[336] = a3;
    }
}

// ---- conv1 + BN + ReLU on [0,115)^2 -> channel-last bf16 h1c[b][r][c][64] ----
// thread = pixel, all 64 ic; weights via wave-uniform s_load (SGPR-operand FMA);
// coalesced 16B stores through swizzled LDS transpose. grid (52, 32), 256 thr.
__global__ __launch_bounds__(256) void conv1_kernel(const float* __restrict__ Xd,
                                                    const float* __restrict__ ws1,
                                                    const float* __restrict__ wb1,
                                                    unsigned short* __restrict__ h1c) {
    const int b = blockIdx.y;
    const int p0 = blockIdx.x * 256;
    const int tid = threadIdx.x;
    const int p = p0 + tid;
    __shared__ uint4 Lt[2048];        // 32KB: [px][icg ^ (px&7)]

    const bool valid = p < NPX1;
    int r = p / H1DIM, c = p - r * H1DIM;
    const float* X = Xd + (size_t)b * KEEP * KEEP;
    float xv[9];
#pragma unroll
    for (int ky = 0; ky < 3; ++ky)
#pragma unroll
        for (int kx = 0; kx < 3; ++kx) {
            int rr = r + ky - 1, cc = c + kx - 1;
            xv[ky * 3 + kx] =
                (valid && (unsigned)rr < (unsigned)KEEP && (unsigned)cc < (unsigned)KEEP)
                    ? X[rr * KEEP + cc] : 0.f;
        }

#pragma unroll 1
    for (int icg = 0; icg < 8; ++icg) {
        union { unsigned short us[8]; uint4 v; } u;
#pragma unroll
        for (int j = 0; j < 8; ++j) {
            int ic = icg * 8 + j;
            float s = wb1[ic];        // uniform -> s_load
#pragma unroll
            for (int t = 0; t < 9; ++t) s = fmaf(xv[t], ws1[ic * 9 + t], s);
            u.us[j] = f2bf(fmaxf(s, 0.f));
        }
        Lt[tid * 8 + (icg ^ (tid & 7))] = u.v;
    }
    __syncthreads();

#pragma unroll
    for (int k = 0; k < 8; ++k) {
        int q = k * 256 + tid;
        int pxl = q >> 3, ig = q & 7;
        uint4 v = Lt[pxl * 8 + (ig ^ (pxl & 7))];
        int pg = p0 + pxl;
        if (pg < NPX1)
            *reinterpret_cast<uint4*>(h1c + ((size_t)b * NPX1 + pg) * 64 + ig * 8) = v;
    }
}

// ---- conv2 via bf16 MFMA 32x32x16: 9-tap shifted implicit GEMM ----
// grid (8 tc, 8 tr, 32 b), block 512 = 8 waves = 4 mg x 2 og.
// LDS layout: byte addr = px*128 + 32*(kc^(px&3)) + 16*(h^((px>>2)&1)).
// 9 precomputed base addrs; per step: 1 xor (F0) + xor+add (F1) -> 3 VALU.
__global__ __launch_bounds__(512, 4) void conv2_mfma_kernel(
    const unsigned short* __restrict__ h1c, const uint4* __restrict__ w2f,
    const float* __restrict__ b2, const float* __restrict__ g2,
    const float* __restrict__ be2, const float* __restrict__ m2,
    const float* __restrict__ v2, float* __restrict__ partial) {
    const int tc = blockIdx.x, tr = blockIdx.y, b = blockIdx.z;
    const int r0 = tr * 16, c0 = tc * 16;
    const int tid = threadIdx.x;
    const int lane = tid & 63, w = tid >> 6;
    const int mg = w & 3, og = w >> 2;

    __shared__ unsigned short At[324 * 64];   // 41472 B

    // stage A tile: rows r0-1..r0+16, cols c0-1..c0+16, 64 ic = 8 granules of 16B
    const unsigned short* __restrict__ h1b = h1c + (size_t)b * (NPX1 * 64);
    char* Atw = reinterpret_cast<char*>(At);
    for (int e = tid; e < 2592; e += 512) {
        int px = e >> 3, gi = e & 7;
        int pr = px / 18, pc = px - pr * 18;
        int gr = r0 + pr - 1, gc = c0 + pc - 1;
        uint4 v = make_uint4(0u, 0u, 0u, 0u);
        if ((unsigned)gr < (unsigned)H1DIM && (unsigned)gc < (unsigned)H1DIM)
            v = *reinterpret_cast<const uint4*>(h1b + ((size_t)(gr * H1DIM + gc)) * 64 + gi * 8);
        int off = px * 128 + 32 * ((gi >> 1) ^ (px & 3)) + 16 * ((gi & 1) ^ ((px >> 2) & 1));
        *reinterpret_cast<uint4*>(Atw + off) = v;
    }
    __syncthreads();

    f32x16 acc[2][2];
#pragma unroll
    for (int F = 0; F < 2; ++F)
#pragma unroll
        for (int N = 0; N < 2; ++N)
#pragma unroll
            for (int i = 0; i < 16; ++i) acc[F][N][i] = 0.f;

    const int flim2 = ADIM - r0 - 4 * mg;    // wave-uniform
    // 9 base byte-addrs (F=0): A0[ky*3+kx]; F=1 read = (A0^16)+4608 (px+36)
    int A0[9];
    {
        const int prb = 4 * mg + ((lane & 31) >> 4);
        const int cb = lane & 15;
        const int hb = lane >> 5;
#pragma unroll
        for (int ky = 0; ky < 3; ++ky)
#pragma unroll
            for (int kx = 0; kx < 3; ++kx) {
                int px = (prb + ky) * 18 + cb + kx;
                A0[ky * 3 + kx] = px * 128 + 32 * (px & 3) + 16 * (hb ^ ((px >> 2) & 1));
            }
    }
    const char* Atc = reinterpret_cast<const char*>(At);

    if (flim2 >= 4) {
#pragma unroll
        for (int s = 0; s < 36; ++s) {
            const int tap = s >> 2, kc = s & 3;
            const int ky = tap / 3, kx = tap - 3 * ky;
            const bf16x8* bq = reinterpret_cast<const bf16x8*>(
                w2f + (size_t)(((tap * 4 + kc) * 4) + og * 2) * 64 + lane);
            const bf16x8 b0 = bq[0];
            const bf16x8 b1 = bq[64];
            const int a0 = A0[ky * 3 + kx] ^ (kc << 5);
            const int a1 = (a0 ^ 16) + 4608;
            const bf16x8 va0 = *reinterpret_cast<const bf16x8*>(Atc + a0);
            const bf16x8 va1 = *reinterpret_cast<const bf16x8*>(Atc + a1);
            acc[0][0] = __builtin_amdgcn_mfma_f32_32x32x16_bf16(va0, b0, acc[0][0], 0, 0, 0);
            acc[0][1] = __builtin_amdgcn_mfma_f32_32x32x16_bf16(va0, b1, acc[0][1], 0, 0, 0);
            acc[1][0] = __builtin_amdgcn_mfma_f32_32x32x16_bf16(va1, b0, acc[1][0], 0, 0, 0);
            acc[1][1] = __builtin_amdgcn_mfma_f32_32x32x16_bf16(va1, b1, acc[1][1], 0, 0, 0);
        }
    } else if (flim2 > 0) {                  // tr==7, mg==0: F=0 only
#pragma unroll
        for (int s = 0; s < 36; ++s) {
            const int tap = s >> 2, kc = s & 3;
            const int ky = tap / 3, kx = tap - 3 * ky;
            const bf16x8* bq = reinterpret_cast<const bf16x8*>(
                w2f + (size_t)(((tap * 4 + kc) * 4) + og * 2) * 64 + lane);
            const bf16x8 b0 = bq[0];
            const bf16x8 b1 = bq[64];
            const int a0 = A0[ky * 3 + kx] ^ (kc << 5);
            const bf16x8 va0 = *reinterpret_cast<const bf16x8*>(Atc + a0);
            acc[0][0] = __builtin_amdgcn_mfma_f32_32x32x16_bf16(va0, b0, acc[0][0], 0, 0, 0);
            acc[0][1] = __builtin_amdgcn_mfma_f32_32x32x16_bf16(va0, b1, acc[0][1], 0, 0, 0);
        }
    }

    // epilogue: BN+ReLU, mask to region A, reduce over pixels, write partials
    // C/D 32x32 map: col(oc-within-32)=lane&31, m=(reg&3)+8*(reg>>2)+4*(lane>>5)
    const int tile = tr * 8 + tc;
    float* pslice = partial + (((size_t)b * 64 + tile) * 4 + mg) * 128;
#pragma unroll
    for (int N = 0; N < 2; ++N) {
        int oc = og * 64 + N * 32 + (lane & 31);
        float sc = g2[oc] * rsqrtf(v2[oc] + 1e-5f);
        float bias = b2[oc] - m2[oc];
        float add = be2[oc];
        float s = 0.f;
#pragma unroll
        for (int F = 0; F < 2; ++F) {
#pragma unroll
            for (int rg = 0; rg < 16; ++rg) {
                int m = (rg & 3) + 8 * (rg >> 2) + 4 * (lane >> 5);
                int p = ((2 * mg + F) << 5) + m;
                int row = r0 + (p >> 4);
                int col = c0 + (p & 15);
                float v = fmaxf(fmaf(acc[F][N][rg] + bias, sc, add), 0.f);
                s += (row < ADIM && col < ADIM) ? v : 0.f;
            }
        }
        s += __shfl_xor(s, 32);
        if (lane < 32) pslice[og * 64 + N * 32 + lane] = s;
    }
}

// ---- reduce partials + analytic constant regions -> mean[b][oc] ----
// grid (32 b, 8 ocg), 256 thr: thread (jq 0..15, ocl 0..15); 16-deep chains.
__global__ __launch_bounds__(256) void reduce_mean_kernel(
    const float* __restrict__ partial, const float* __restrict__ P,
    const float* __restrict__ b2, const float* __restrict__ g2,
    const float* __restrict__ be2, const float* __restrict__ m2,
    const float* __restrict__ v2, float* __restrict__ mean) {
    int b = blockIdx.x, ocg = blockIdx.y;
    int tid = threadIdx.x;
    int ocl = tid & 15, jq = tid >> 4;
    int oc = ocg * 16 + ocl;
    const float* pb = partial + (size_t)b * 256 * 128 + oc;
    float s = 0.f;
#pragma unroll
    for (int jj = 0; jj < 16; ++jj) s += pb[(size_t)(jq * 16 + jj) * 128];
    __shared__ float red[16][17];
    red[jq][ocl] = s;
    __syncthreads();
    if (jq == 0) {
        float tot = 0.f;
#pragma unroll
        for (int k = 0; k < 16; ++k) tot += red[k][ocl];

        float p[9];
#pragma unroll
        for (int t = 0; t < 9; ++t) p[t] = P[oc * 9 + t];

        float Sall = p[0] + p[1] + p[2] + p[3] + p[4] + p[5] + p[6] + p[7] + p[8];
        float Stop = p[3] + p[4] + p[5] + p[6] + p[7] + p[8];
        float Sbot = p[0] + p[1] + p[2] + p[3] + p[4] + p[5];
        float Sleft  = p[1] + p[2] + p[4] + p[5] + p[7] + p[8];
        float Sright = p[0] + p[1] + p[3] + p[4] + p[6] + p[7];
        float Ctr = p[3] + p[4] + p[6] + p[7];
        float Cbl = p[1] + p[2] + p[4] + p[5];
        float Cbr = p[0] + p[1] + p[3] + p[4];

        float bias = b2[oc], mm = m2[oc], bb = be2[oc];
        float sc = g2[oc] * rsqrtf(v2[oc] + 1e-5f);
#define VALOF(S) fmaxf(((bias) + (S) - (mm)) * (sc) + (bb), 0.f)
        float cs = 36515.f * VALOF(Sall) + 109.f * VALOF(Stop) + 109.f * VALOF(Sleft)
                 + 222.f * VALOF(Sbot) + 222.f * VALOF(Sright)
                 + VALOF(Ctr) + VALOF(Cbl) + VALOF(Cbr);
#undef VALOF
        mean[b * 128 + oc] = (tot + cs) * (1.f / (224.f * 224.f));
    }
}

// ---- final linear (float4 weight rows) ----
__global__ __launch_bounds__(256) void final_linear_kernel(const float* __restrict__ mean,
                                                           const float* __restrict__ wp,
                                                           const float* __restrict__ bp,
                                                           float* __restrict__ out) {
    int b = blockIdx.x, e = threadIdx.x;
    __shared__ float mrow[128];
    if (threadIdx.x < 128) mrow[threadIdx.x] = mean[b * 128 + threadIdx.x];
    __syncthreads();
    const float4* wr = reinterpret_cast<const float4*>(wp + (size_t)e * 128);
    float s = bp[e];
#pragma unroll 8
    for (int c = 0; c < 32; ++c) {
        float4 wv = wr[c];
        s = fmaf(mrow[4 * c], wv.x, s);
        s = fmaf(mrow[4 * c + 1], wv.y, s);
        s = fmaf(mrow[4 * c + 2], wv.z, s);
        s = fmaf(mrow[4 * c + 3], wv.w, s);
    }
    out[(size_t)b * 256 + e] = s;
}

extern "C" void kernel_launch(void* const* d_in, const int* in_sizes, int n_in,
                              void* d_out, int out_size, void* d_ws, size_t ws_size,
                              hipStream_t stream) {
    const float* x   = (const float*)d_in[0];
    const float* w1  = (const float*)d_in[1];
    const float* b1  = (const float*)d_in[2];
    const float* g1  = (const float*)d_in[3];
    const float* be1 = (const float*)d_in[4];
    const float* m1  = (const float*)d_in[5];
    const float* v1  = (const float*)d_in[6];
    const float* w2  = (const float*)d_in[7];
    const float* b2  = (const float*)d_in[8];
    const float* g2  = (const float*)d_in[9];
    const float* be2 = (const float*)d_in[10];
    const float* m2  = (const float*)d_in[11];
    const float* v2  = (const float*)d_in[12];
    const float* wp  = (const float*)d_in[13];
    const float* bp  = (const float*)d_in[14];
    float* out = (float*)d_out;

    float* ws = (float*)d_ws;
    size_t off = 0;
    float* Bst  = ws + off; off += (size_t)KEEP * KEEP;          // 12544
    float* tmp1 = ws + off; off += (size_t)32 * NPIX * KEEP;     // 802816
    float* Xd   = ws + off; off += (size_t)32 * KEEP * KEEP;     // 401408
    float* P    = ws + off; off += 128 * 9;
    float* ws1  = ws + off; off += 64 * 9;
    float* wb1  = ws + off; off += 64;
    uint4* w2f  = (uint4*)(ws + off); off += (size_t)9216 * 4;   // 9216 uint4
    float* part = ws + off; off += (size_t)32 * 256 * 128;       // 1048576
    float* mean = ws + off; off += 32 * 128;
    unsigned short* h1c = (unsigned short*)(ws + off);
    off += (size_t)32 * NPX1 * 64 / 2;                           // bf16

    if (ws_size < off * sizeof(float)) return;  // workspace too small: fail visibly

    prep_kernel<<<dim3(91), dim3(256), 0, stream>>>(w1, b1, g1, be1, m1, v1, w2,
                                                    Bst, P, ws1, wb1, w2f);
    dct_w_kernel<<<dim3(32 * 56), dim3(128), 0, stream>>>(x, Bst, tmp1);
    dct_h_kernel<<<dim3(28, 32), dim3(512), 0, stream>>>(tmp1, Bst, Xd);
    conv1_kernel<<<dim3(52, 32), dim3(256), 0, stream>>>(Xd, ws1, wb1, h1c);
    conv2_mfma_kernel<<<dim3(8, 8, 32), dim3(512), 0, stream>>>(
        h1c, w2f, b2, g2, be2, m2, v2, part);
    reduce_mean_kernel<<<dim3(32, 8), dim3(256), 0, stream>>>(part, P, b2, g2, be2, m2, v2, mean);
    final_linear_kernel<<<dim3(32), dim3(256), 0, stream>>>(mean, wp, bp, out);
}